// Round 4
// baseline (830.163 us; speedup 1.0000x reference)
//
#include <hip/hip_runtime.h>

// W8Linear: y[t,o] = sum_k x[t,k] * (wq[o,k]*scale[o]) + bias[o]
// wq in [-127,127] is EXACT in bf16; x->bf16 RNE. cvt prepass -> bf16 GEMM.
// R4: 256x256, BK=32, 8 waves, ring-4 LDS, stage-ahead-3, m201-style phase
// rhythm: per K-tile 2 phases, each {ds_read || gl_lds -> barrier -> lgkm0 ->
// setprio1 -> 16 MFMA -> setprio0 -> barrier}, counted vmcnt(8) once per tile
// (never 0 in main loop). T1 XCD swizzle + T2 LDS XOR swizzle.

#define M_TOK 8192
#define K_DIM 4096
#define N_OUT 11008
#define BM 256
#define BN 256
#define BK 32
#define NT (K_DIM / BK)    // 128 K-tiles
#define NBM (M_TOK / BM)   // 32
#define NBN (N_OUT / BN)   // 43
#define NWG (NBM * NBN)    // 1376 = 8 * 172

typedef __attribute__((ext_vector_type(8))) short bf16x8;
typedef __attribute__((ext_vector_type(4))) short bf16x4;
typedef __attribute__((ext_vector_type(4))) float f32x4;
typedef __attribute__((ext_vector_type(4))) int   i32x4;
typedef unsigned short u16;

__device__ __forceinline__ u16 to_bf16_rne(float f) {
  union { float f; unsigned u; } v; v.f = f;
  return (u16)((v.u + 0x7FFFu + ((v.u >> 16) & 1u)) >> 16);
}

__global__ void cvt_x_kernel(const float* __restrict__ in, u16* __restrict__ out, long n4) {
  long i = (long)blockIdx.x * blockDim.x + threadIdx.x;
  const long stride = (long)gridDim.x * blockDim.x;
  for (; i < n4; i += stride) {
    f32x4 v = ((const f32x4*)in)[i];
    bf16x4 o;
    o.x = (short)to_bf16_rne(v[0]);
    o.y = (short)to_bf16_rne(v[1]);
    o.z = (short)to_bf16_rne(v[2]);
    o.w = (short)to_bf16_rne(v[3]);
    ((bf16x4*)out)[i] = o;
  }
}

__global__ void cvt_w_kernel(const int* __restrict__ in, u16* __restrict__ out, long n4) {
  long i = (long)blockIdx.x * blockDim.x + threadIdx.x;
  const long stride = (long)gridDim.x * blockDim.x;
  for (; i < n4; i += stride) {
    i32x4 v = ((const i32x4*)in)[i];
    bf16x4 o;
    o.x = (short)to_bf16_rne((float)v[0]);
    o.y = (short)to_bf16_rne((float)v[1]);
    o.z = (short)to_bf16_rne((float)v[2]);
    o.w = (short)to_bf16_rne((float)v[3]);
    ((bf16x4*)out)[i] = o;
  }
}

__device__ __forceinline__ void gl_lds16(const u16* g, u16* l) {
  __builtin_amdgcn_global_load_lds(
      (const __attribute__((address_space(1))) void*)g,
      (__attribute__((address_space(3))) void*)l,
      16, 0, 0);
}

// One K-tile, template rhythm. ST: staging active (stages tile T+3).
// CNTASM: the end-of-tile counted vmcnt.
#define TILE(T, ST, CNTASM) do { \
    const char* pa_ = ldsc + ((T) & 3) * 32768 + abase; \
    const char* pb_ = ldsc + ((T) & 3) * 32768 + bbase; \
    u16* wsl_ = lds + (((T) + 3) & 3) * 16384; \
    const int ko_ = ((T) + 3) * BK; \
    /* ---- phase 1: read af+bv | stage A(t+3) | bar | lgkm0 | 16 MFMA | bar */ \
    bf16x8 af[4], bv[4]; \
    _Pragma("unroll") \
    for (int m = 0; m < 4; ++m) af[m] = *(const bf16x8*)(pa_ + m * 1024); \
    _Pragma("unroll") \
    for (int n = 0; n < 4; ++n) bv[n] = *(const bf16x8*)(pb_ + n * 1024); \
    if (ST) { \
      gl_lds16(pA0 + ko_, wsl_ + dwa); \
      gl_lds16(pA1 + ko_, wsl_ + 4096 + dwa); \
    } \
    __builtin_amdgcn_s_barrier(); \
    asm volatile("s_waitcnt lgkmcnt(0)" ::: "memory"); \
    __builtin_amdgcn_sched_barrier(0); \
    __builtin_amdgcn_s_setprio(1); \
    _Pragma("unroll") \
    for (int m = 0; m < 4; ++m) \
      _Pragma("unroll") \
      for (int n = 0; n < 4; ++n) \
        acc[m][n] = __builtin_amdgcn_mfma_f32_16x16x32_bf16(af[m], bv[n], acc[m][n], 0, 0, 0); \
    __builtin_amdgcn_s_setprio(0); \
    __builtin_amdgcn_s_barrier(); \
    /* ---- phase 2: read ag | stage B(t+3) | bar | lgkm0 | 16 MFMA | vmcnt | bar */ \
    bf16x8 ag[4]; \
    _Pragma("unroll") \
    for (int m = 0; m < 4; ++m) ag[m] = *(const bf16x8*)(pa_ + (m + 4) * 1024); \
    if (ST) { \
      gl_lds16(pB0 + ko_, wsl_ + 8192 + dwa); \
      gl_lds16(pB1 + ko_, wsl_ + 12288 + dwa); \
    } \
    __builtin_amdgcn_s_barrier(); \
    asm volatile("s_waitcnt lgkmcnt(0)" ::: "memory"); \
    __builtin_amdgcn_sched_barrier(0); \
    __builtin_amdgcn_s_setprio(1); \
    _Pragma("unroll") \
    for (int m = 0; m < 4; ++m) \
      _Pragma("unroll") \
      for (int n = 0; n < 4; ++n) \
        acc[m + 4][n] = __builtin_amdgcn_mfma_f32_16x16x32_bf16(ag[m], bv[n], acc[m + 4][n], 0, 0, 0); \
    __builtin_amdgcn_s_setprio(0); \
    asm volatile(CNTASM ::: "memory"); \
    __builtin_amdgcn_sched_barrier(0); \
    __builtin_amdgcn_s_barrier(); \
  } while (0)

__global__ __launch_bounds__(512, 2) void gemm256(
    const u16* __restrict__ A, const u16* __restrict__ B,
    const float* __restrict__ scale, const float* __restrict__ bias,
    float* __restrict__ C) {
  __shared__ u16 lds[65536];  // 128 KiB: 4 ring slots x (A 16KB + B 16KB)

  const int tid  = threadIdx.x;
  const int lane = tid & 63;
  const int wave = tid >> 6;
  const int wm = wave >> 2;  // 0..1
  const int wn = wave & 3;   // 0..3

  // T1: XCD-aware bijective swizzle (NWG % 8 == 0)
  const int swz = (blockIdx.x & 7) * (NWG / 8) + (blockIdx.x >> 3);
  const int bm = swz / NBN;
  const int bn = swz % NBN;
  const long m0 = (long)bm * BM;
  const long n0 = (long)bn * BN;

  // ---- staging source (pre-swizzled global; rule #21) ----
  const int rs = tid >> 2;  // 0..127 (row within 128-row chunk)
  const int cs = ((tid & 3) * 8) ^ (((rs >> 1) & 3) << 3);
  const u16* pA0 = A + (m0 + rs) * (long)K_DIM + cs;
  const u16* pA1 = pA0 + 128L * K_DIM;
  const u16* pB0 = B + (n0 + rs) * (long)K_DIM + cs;
  const u16* pB1 = pB0 + 128L * K_DIM;
  const int dwa = wave * 512;  // u16: wave's 1KB segment within an 8KB chunk

  // ---- fragment read offsets (bytes, T2-swizzled) ----
  const int inner = ((lane >> 4) * 16) ^ ((((lane & 15) >> 1) & 3) << 4);
  const int abase = (wm * 128 + (lane & 15)) * 64 + inner;           // A region
  const int bbase = 16384 + (wn * 64 + (lane & 15)) * 64 + inner;    // B region
  const char* ldsc = (const char*)lds;

  f32x4 acc[8][4] = {};

  // ---- prologue: stage tiles 0,1,2 (12 loads); vmcnt(8) -> tile 0 landed ----
#pragma unroll
  for (int p = 0; p < 3; ++p) {
    u16* wsl = lds + p * 16384;
    const int ko = p * BK;
    gl_lds16(pA0 + ko, wsl + dwa);
    gl_lds16(pA1 + ko, wsl + 4096 + dwa);
    gl_lds16(pB0 + ko, wsl + 8192 + dwa);
    gl_lds16(pB1 + ko, wsl + 12288 + dwa);
  }
  asm volatile("s_waitcnt vmcnt(8)" ::: "memory");
  __builtin_amdgcn_sched_barrier(0);
  __builtin_amdgcn_s_barrier();

  // main: stage-ahead active, counted vmcnt(8) = "next tile ready"
  for (int t = 0; t < NT - 3; ++t) {
    TILE(t, 1, "s_waitcnt vmcnt(8)");
  }
  // tail ledger: end NT-3 -> vmcnt(4) (NT-2 ready); end NT-2 -> vmcnt(0)
  TILE(NT - 3, 0, "s_waitcnt vmcnt(4)");
  TILE(NT - 2, 0, "s_waitcnt vmcnt(0)");
  TILE(NT - 1, 0, "s_waitcnt vmcnt(0)");

  // ---- epilogue: scale/bias, f32 store ----
  // C/D layout: col = lane&15, row = (lane>>4)*4 + v   [m89/m91]
  const int crow = (lane >> 4) * 4;
  const int ccol = lane & 15;
#pragma unroll
  for (int n = 0; n < 4; ++n) {
    const long col = n0 + wn * 64 + n * 16 + ccol;
    const float sc = scale[col];
    const float bz = bias[col];
#pragma unroll
    for (int m = 0; m < 8; ++m) {
      const long row = m0 + wm * 128 + m * 16 + crow;
      f32x4 a = acc[m][n];
#pragma unroll
      for (int v = 0; v < 4; ++v)
        C[(row + v) * (long)N_OUT + col] = a[v] * sc + bz;
    }
  }
}

// ---------- fallback (ws too small): 128^2 convert-in-kernel ----------
__global__ __launch_bounds__(256) void gemm_cvt(
    const float* __restrict__ X, const int* __restrict__ W,
    const float* __restrict__ scale, const float* __restrict__ bias,
    float* __restrict__ C) {
  __shared__ u16 lds_a[128 * 32];
  __shared__ u16 lds_b[128 * 32];

  const int tid  = threadIdx.x;
  const int lane = tid & 63;
  const int wave = tid >> 6;
  const int wm = wave >> 1, wn = wave & 1;

  const long m0 = (long)blockIdx.y * 128;
  const long n0 = (long)blockIdx.x * 128;

  const int arow = tid >> 3;
  const int acol = (tid & 7) * 4;

  const float* gX = X + (m0 + arow) * (long)K_DIM + acol;
  const int*   gW = W + (n0 + arow) * (long)K_DIM + acol;

  u16* wla = lds_a + arow * 32 + acol;
  u16* wlb = lds_b + arow * 32 + acol;

  f32x4 acc[4][4] = {};
  const int fr = lane & 15;
  const int fk = (lane >> 4) * 8;
  const u16* fa = lds_a + (wm * 64 + fr) * 32 + fk;
  const u16* fb = lds_b + (wn * 64 + fr) * 32 + fk;

  for (int kk = 0; kk < K_DIM / 32; ++kk) {
    const long ko = (long)kk * 32;
    f32x4 xv[4]; i32x4 wv[4];
#pragma unroll
    for (int j = 0; j < 4; ++j) {
      xv[j] = *(const f32x4*)(gX + (long)j * 32 * K_DIM + ko);
      wv[j] = *(const i32x4*)(gW + (long)j * 32 * K_DIM + ko);
    }
    __syncthreads();
#pragma unroll
    for (int j = 0; j < 4; ++j) {
      bf16x4 oa, ob;
      oa.x = (short)to_bf16_rne(xv[j][0]);
      oa.y = (short)to_bf16_rne(xv[j][1]);
      oa.z = (short)to_bf16_rne(xv[j][2]);
      oa.w = (short)to_bf16_rne(xv[j][3]);
      ob.x = (short)to_bf16_rne((float)wv[j][0]);
      ob.y = (short)to_bf16_rne((float)wv[j][1]);
      ob.z = (short)to_bf16_rne((float)wv[j][2]);
      ob.w = (short)to_bf16_rne((float)wv[j][3]);
      *(bf16x4*)(wla + j * 32 * 32) = oa;
      *(bf16x4*)(wlb + j * 32 * 32) = ob;
    }
    __syncthreads();

    bf16x8 af[4], bfr[4];
#pragma unroll
    for (int m = 0; m < 4; ++m) af[m] = *(const bf16x8*)(fa + m * 16 * 32);
#pragma unroll
    for (int n = 0; n < 4; ++n) bfr[n] = *(const bf16x8*)(fb + n * 16 * 32);
#pragma unroll
    for (int m = 0; m < 4; ++m)
#pragma unroll
      for (int n = 0; n < 4; ++n)
        acc[m][n] = __builtin_amdgcn_mfma_f32_16x16x32_bf16(af[m], bfr[n], acc[m][n], 0, 0, 0);
  }

  const int crow = (lane >> 4) * 4;
  const int ccol = lane & 15;
#pragma unroll
  for (int n = 0; n < 4; ++n) {
    const long col = n0 + wn * 64 + n * 16 + ccol;
    const float sc = scale[col];
    const float bz = bias[col];
#pragma unroll
    for (int m = 0; m < 4; ++m) {
      const long row = m0 + wm * 64 + m * 16 + crow;
      f32x4 a = acc[m][n];
#pragma unroll
      for (int v = 0; v < 4; ++v)
        C[(row + v) * (long)N_OUT + col] = a[v] * sc + bz;
    }
  }
}

extern "C" void kernel_launch(void* const* d_in, const int* in_sizes, int n_in,
                              void* d_out, int out_size, void* d_ws, size_t ws_size,
                              hipStream_t stream) {
  const float* x  = (const float*)d_in[0];
  const int*   wq = (const int*)d_in[1];
  const float* mx = (const float*)d_in[2];
  const float* bs = (const float*)d_in[3];
  float* out = (float*)d_out;

  const size_t needA = (size_t)M_TOK * K_DIM * sizeof(u16);
  const size_t needB = (size_t)N_OUT * K_DIM * sizeof(u16);

  if (ws_size >= needA + needB) {
    u16* xb = (u16*)d_ws;
    u16* wb = xb + (size_t)M_TOK * K_DIM;
    cvt_x_kernel<<<2048, 256, 0, stream>>>(x, xb, (long)M_TOK * K_DIM / 4);
    cvt_w_kernel<<<2048, 256, 0, stream>>>(wq, wb, (long)N_OUT * K_DIM / 4);
    gemm256<<<dim3(NWG), dim3(512), 0, stream>>>(xb, wb, mx, bs, out);
  } else {
    dim3 grid(N_OUT / 128, M_TOK / 128);
    gemm_cvt<<<grid, 256, 0, stream>>>(x, wq, mx, bs, out);
  }
}

// Round 5
// 497.064 us; speedup vs baseline: 1.6701x; 1.6701x over previous
//
#include <hip/hip_runtime.h>

// W8Linear: y[t,o] = sum_k x[t,k] * (wq[o,k]*scale[o]) + bias[o]
// R5: INT8 MFMA path. wq is exactly int8; x quantized per-token:
//   sx[t] = absmax(x[t,:])/127, xq = rint(x/sx) in [-127,127]
//   y = (i32 mfma acc) * (scale[o]*sx[t]) + bias[o]
// i32 accumulation exact; only x-quant error: absmax ~4-5 << 9.28 threshold.
// GEMM = R3's proven structure (ring-4 LDS, stage-ahead-3, one barrier/tile,
// counted vmcnt(4), frag read-ahead, setprio, T1 XCD + T2 LDS swizzle) with
// mfma_i32_16x16x64_i8 (K=64/instr, 2x rate, half LDS+stage bytes).

#define M_TOK 8192
#define K_DIM 4096
#define N_OUT 11008
#define BM 256
#define BN 256
#define BK 64                // i8 k per tile (row stride 64 B, same as bf16@BK32)
#define NT (K_DIM / BK)      // 64 K-tiles
#define NBM (M_TOK / BM)     // 32
#define NBN (N_OUT / BN)     // 43
#define NWG (NBM * NBN)      // 1376 = 8 * 172

typedef __attribute__((ext_vector_type(4))) int   i32x4;
typedef __attribute__((ext_vector_type(4))) float f32x4;
typedef __attribute__((ext_vector_type(4))) short bf16x4;
typedef __attribute__((ext_vector_type(8))) short bf16x8;
typedef unsigned short u16;
typedef signed char i8;
typedef unsigned char u8;

// ---------------- prepass: per-token quantize x -> i8 + sx ----------------
__global__ __launch_bounds__(256) void quant_x(const float* __restrict__ x,
                                               i8* __restrict__ xq,
                                               float* __restrict__ sx) {
  const int t = blockIdx.x;          // token
  const int tid = threadIdx.x;       // 256 threads; 16 elems each
  const float* row = x + (long)t * K_DIM;
  f32x4 v[4];
  float mx = 0.0f;
#pragma unroll
  for (int j = 0; j < 4; ++j) {
    v[j] = ((const f32x4*)row)[tid * 4 + j];
#pragma unroll
    for (int e = 0; e < 4; ++e) mx = fmaxf(mx, fabsf(v[j][e]));
  }
#pragma unroll
  for (int off = 32; off >= 1; off >>= 1) mx = fmaxf(mx, __shfl_xor(mx, off));
  __shared__ float wmx[4];
  if ((tid & 63) == 0) wmx[tid >> 6] = mx;
  __syncthreads();
  mx = fmaxf(fmaxf(wmx[0], wmx[1]), fmaxf(wmx[2], wmx[3]));
  const float sxinv = (mx > 0.0f) ? 127.0f / mx : 0.0f;
  if (tid == 0) sx[t] = (mx > 0.0f) ? mx / 127.0f : 0.0f;
  i32x4 out;
#pragma unroll
  for (int j = 0; j < 4; ++j) {
    int q0 = __float2int_rn(v[j][0] * sxinv);
    int q1 = __float2int_rn(v[j][1] * sxinv);
    int q2 = __float2int_rn(v[j][2] * sxinv);
    int q3 = __float2int_rn(v[j][3] * sxinv);
    q0 = max(-127, min(127, q0)); q1 = max(-127, min(127, q1));
    q2 = max(-127, min(127, q2)); q3 = max(-127, min(127, q3));
    out[j] = (q0 & 255) | ((q1 & 255) << 8) | ((q2 & 255) << 16) | ((q3 & 255) << 24);
  }
  ((i32x4*)(xq + (long)t * K_DIM))[tid] = out;
}

// ---------------- prepass: pack w int32 -> int8 (exact) ----------------
__global__ void pack_w(const int* __restrict__ in, i8* __restrict__ out, long n16) {
  long i = (long)blockIdx.x * blockDim.x + threadIdx.x;
  const long stride = (long)gridDim.x * blockDim.x;
  for (; i < n16; i += stride) {
    i32x4 o;
#pragma unroll
    for (int j = 0; j < 4; ++j) {
      i32x4 w = ((const i32x4*)in)[i * 4 + j];
      o[j] = (w[0] & 255) | ((w[1] & 255) << 8) | ((w[2] & 255) << 16) | ((w[3] & 255) << 24);
    }
    ((i32x4*)out)[i] = o;
  }
}

__device__ __forceinline__ void gl_lds16(const i8* g, u8* l) {
  __builtin_amdgcn_global_load_lds(
      (const __attribute__((address_space(1))) void*)g,
      (__attribute__((address_space(3))) void*)l,
      16, 0, 0);
}

// stage all 4 chunks (A0,A1,B0,B1) of K-tile T into ring slot T&3 (32 KB/slot)
#define STAGE(T) do { \
    u8* wsl = lds + ((T) & 3) * 32768; \
    const int ko = (T) * BK; \
    gl_lds16(pA0 + ko, wsl + dwa); \
    gl_lds16(pA1 + ko, wsl + 8192 + dwa); \
    gl_lds16(pB0 + ko, wsl + 16384 + dwa); \
    gl_lds16(pB1 + ko, wsl + 24576 + dwa); \
  } while (0)

// One K-tile (R3 structure): AFC/BVC current frags, AFN/BVN next, RA = read-ahead
#define TILE_BODY(T, AFC, BVC, AFN, BVN, RA) do { \
    const char* pa_ = ldsc + ((T) & 3) * 32768 + abase; \
    _Pragma("unroll") \
    for (int m = 0; m < 4; ++m) ag[m] = *(const i32x4*)(pa_ + (m + 4) * 1024); \
    if ((T) <= NT - 4) STAGE((T) + 3); \
    __builtin_amdgcn_s_setprio(1); \
    _Pragma("unroll") \
    for (int m = 0; m < 4; ++m) \
      _Pragma("unroll") \
      for (int n = 0; n < 4; ++n) \
        acc[m][n] = __builtin_amdgcn_mfma_i32_16x16x64_i8(AFC[m], BVC[n], acc[m][n], 0, 0, 0); \
    __builtin_amdgcn_s_setprio(0); \
    if (RA) { \
      const char* qa_ = ldsc + (((T) + 1) & 3) * 32768 + abase; \
      const char* qb_ = ldsc + (((T) + 1) & 3) * 32768 + bbase; \
      _Pragma("unroll") \
      for (int m = 0; m < 4; ++m) AFN[m] = *(const i32x4*)(qa_ + m * 1024); \
      _Pragma("unroll") \
      for (int n = 0; n < 4; ++n) BVN[n] = *(const i32x4*)(qb_ + n * 1024); \
    } \
    __builtin_amdgcn_s_setprio(1); \
    _Pragma("unroll") \
    for (int m = 0; m < 4; ++m) \
      _Pragma("unroll") \
      for (int n = 0; n < 4; ++n) \
        acc[m + 4][n] = __builtin_amdgcn_mfma_i32_16x16x64_i8(ag[m], BVC[n], acc[m + 4][n], 0, 0, 0); \
    __builtin_amdgcn_s_setprio(0); \
    if ((T) <= NT - 4) { asm volatile("s_waitcnt vmcnt(4)" ::: "memory"); } \
    else               { asm volatile("s_waitcnt vmcnt(0)" ::: "memory"); } \
    __builtin_amdgcn_sched_barrier(0); \
    __builtin_amdgcn_s_barrier(); \
  } while (0)

__global__ __launch_bounds__(512, 2) void gemm_i8(
    const i8* __restrict__ A, const i8* __restrict__ B,
    const float* __restrict__ sx, const float* __restrict__ scale,
    const float* __restrict__ bias, float* __restrict__ C) {
  __shared__ u8 lds[131072];  // 4 ring slots x (A 16KB + B 16KB)

  const int tid  = threadIdx.x;
  const int lane = tid & 63;
  const int wave = tid >> 6;
  const int wm = wave >> 2;  // 0..1
  const int wn = wave & 3;   // 0..3

  // T1: XCD-aware bijective swizzle (NWG % 8 == 0)
  const int swz = (blockIdx.x & 7) * (NWG / 8) + (blockIdx.x >> 3);
  const int bm = swz / NBN;
  const int bn = swz % NBN;
  const long m0 = (long)bm * BM;
  const long n0 = (long)bn * BN;

  // ---- staging source (pre-swizzled global; rule #21) ----
  // thread t writes LDS chunk byte t*16: row r = t>>2 (64 B rows), col (t&3)*16
  const int rs = tid >> 2;  // 0..127
  const int cs = ((tid & 3) * 16) ^ ((((rs >> 1) & 3)) << 4);  // byte==i8 units
  const i8* pA0 = A + (m0 + rs) * (long)K_DIM + cs;
  const i8* pA1 = pA0 + 128L * K_DIM;
  const i8* pB0 = B + (n0 + rs) * (long)K_DIM + cs;
  const i8* pB1 = pB0 + 128L * K_DIM;
  const int dwa = wave * 1024;  // wave's segment within an 8KB chunk

  // ---- fragment read offsets (bytes, T2-swizzled; identical math to R3) ----
  const int inner = ((lane >> 4) * 16) ^ ((((lane & 15) >> 1) & 3) << 4);
  const int abase = (wm * 128 + (lane & 15)) * 64 + inner;            // A region
  const int bbase = 16384 + (wn * 64 + (lane & 15)) * 64 + inner;     // B region
  const char* ldsc = (const char*)lds;

  i32x4 acc[8][4] = {};
  i32x4 afE[4], bvE[4], afO[4], bvO[4], ag[4];

  // ---- prologue: stage tiles 0,1,2; wait 0,1 landed; preload frags(0) ----
  STAGE(0); STAGE(1); STAGE(2);
  asm volatile("s_waitcnt vmcnt(4)" ::: "memory");
  __builtin_amdgcn_sched_barrier(0);
  __builtin_amdgcn_s_barrier();
  {
    const char* qa = ldsc + abase;
    const char* qb = ldsc + bbase;
#pragma unroll
    for (int m = 0; m < 4; ++m) afE[m] = *(const i32x4*)(qa + m * 1024);
#pragma unroll
    for (int n = 0; n < 4; ++n) bvE[n] = *(const i32x4*)(qb + n * 1024);
  }

  for (int t = 0; t < NT - 2; t += 2) {
    TILE_BODY(t,     afE, bvE, afO, bvO, 1);
    TILE_BODY(t + 1, afO, bvO, afE, bvE, 1);
  }
  TILE_BODY(NT - 2, afE, bvE, afO, bvO, 1);
  TILE_BODY(NT - 1, afO, bvO, afE, bvE, 0);

  // ---- epilogue: y = acc * (scale[col]*sx[row]) + bias[col] ----
  // C/D layout: col = lane&15, row = (lane>>4)*4 + v  (dtype-independent)
  const int crow = (lane >> 4) * 4;
  const int ccol = lane & 15;
  float sxa[8][4];
#pragma unroll
  for (int m = 0; m < 8; ++m)
#pragma unroll
    for (int v = 0; v < 4; ++v)
      sxa[m][v] = sx[m0 + wm * 128 + m * 16 + crow + v];
#pragma unroll
  for (int n = 0; n < 4; ++n) {
    const long col = n0 + wn * 64 + n * 16 + ccol;
    const float sc = scale[col];
    const float bz = bias[col];
#pragma unroll
    for (int m = 0; m < 8; ++m) {
      const long row = m0 + wm * 128 + m * 16 + crow;
      i32x4 a = acc[m][n];
#pragma unroll
      for (int v = 0; v < 4; ++v)
        C[(row + v) * (long)N_OUT + col] = (float)a[v] * (sc * sxa[m][v]) + bz;
    }
  }
}

// ---------- fallback (ws too small): 128^2 convert-in-kernel bf16 ----------
__device__ __forceinline__ u16 to_bf16_rne(float f) {
  union { float f; unsigned u; } v; v.f = f;
  return (u16)((v.u + 0x7FFFu + ((v.u >> 16) & 1u)) >> 16);
}

__global__ __launch_bounds__(256) void gemm_cvt(
    const float* __restrict__ X, const int* __restrict__ W,
    const float* __restrict__ scale, const float* __restrict__ bias,
    float* __restrict__ C) {
  __shared__ u16 lds_a[128 * 32];
  __shared__ u16 lds_b[128 * 32];

  const int tid  = threadIdx.x;
  const int lane = tid & 63;
  const int wave = tid >> 6;
  const int wm = wave >> 1, wn = wave & 1;

  const long m0 = (long)blockIdx.y * 128;
  const long n0 = (long)blockIdx.x * 128;

  const int arow = tid >> 3;
  const int acol = (tid & 7) * 4;

  const float* gX = X + (m0 + arow) * (long)K_DIM + acol;
  const int*   gW = W + (n0 + arow) * (long)K_DIM + acol;

  u16* wla = lds_a + arow * 32 + acol;
  u16* wlb = lds_b + arow * 32 + acol;

  f32x4 acc[4][4] = {};
  const int fr = lane & 15;
  const int fk = (lane >> 4) * 8;
  const u16* fa = lds_a + (wm * 64 + fr) * 32 + fk;
  const u16* fb = lds_b + (wn * 64 + fr) * 32 + fk;

  for (int kk = 0; kk < K_DIM / 32; ++kk) {
    const long ko = (long)kk * 32;
    f32x4 xv[4]; i32x4 wv[4];
#pragma unroll
    for (int j = 0; j < 4; ++j) {
      xv[j] = *(const f32x4*)(gX + (long)j * 32 * K_DIM + ko);
      wv[j] = *(const i32x4*)(gW + (long)j * 32 * K_DIM + ko);
    }
    __syncthreads();
#pragma unroll
    for (int j = 0; j < 4; ++j) {
      bf16x4 oa, ob;
      oa.x = (short)to_bf16_rne(xv[j][0]);
      oa.y = (short)to_bf16_rne(xv[j][1]);
      oa.z = (short)to_bf16_rne(xv[j][2]);
      oa.w = (short)to_bf16_rne(xv[j][3]);
      ob.x = (short)to_bf16_rne((float)wv[j][0]);
      ob.y = (short)to_bf16_rne((float)wv[j][1]);
      ob.z = (short)to_bf16_rne((float)wv[j][2]);
      ob.w = (short)to_bf16_rne((float)wv[j][3]);
      *(bf16x4*)(wla + j * 32 * 32) = oa;
      *(bf16x4*)(wlb + j * 32 * 32) = ob;
    }
    __syncthreads();

    bf16x8 af[4], bfr[4];
#pragma unroll
    for (int m = 0; m < 4; ++m) af[m] = *(const bf16x8*)(fa + m * 16 * 32);
#pragma unroll
    for (int n = 0; n < 4; ++n) bfr[n] = *(const bf16x8*)(fb + n * 16 * 32);
#pragma unroll
    for (int m = 0; m < 4; ++m)
#pragma unroll
      for (int n = 0; n < 4; ++n)
        acc[m][n] = __builtin_amdgcn_mfma_f32_16x16x32_bf16(af[m], bfr[n], acc[m][n], 0, 0, 0);
  }

  const int crow = (lane >> 4) * 4;
  const int ccol = lane & 15;
#pragma unroll
  for (int n = 0; n < 4; ++n) {
    const long col = n0 + wn * 64 + n * 16 + ccol;
    const float sc = scale[col];
    const float bz = bias[col];
#pragma unroll
    for (int m = 0; m < 4; ++m) {
      const long row = m0 + wm * 64 + m * 16 + crow;
      f32x4 a = acc[m][n];
#pragma unroll
      for (int v = 0; v < 4; ++v)
        C[(row + v) * (long)N_OUT + col] = a[v] * sc + bz;
    }
  }
}

extern "C" void kernel_launch(void* const* d_in, const int* in_sizes, int n_in,
                              void* d_out, int out_size, void* d_ws, size_t ws_size,
                              hipStream_t stream) {
  const float* x  = (const float*)d_in[0];
  const int*   wq = (const int*)d_in[1];
  const float* mx = (const float*)d_in[2];
  const float* bs = (const float*)d_in[3];
  float* out = (float*)d_out;

  const size_t szXQ = (size_t)M_TOK * K_DIM;            // 33.5 MB i8
  const size_t szWQ = (size_t)N_OUT * K_DIM;            // 45 MB i8
  const size_t szSX = (size_t)M_TOK * sizeof(float);    // 32 KB
  if (ws_size >= szXQ + szWQ + szSX) {
    i8* xq = (i8*)d_ws;
    i8* wq8 = xq + szXQ;
    float* sx = (float*)(wq8 + szWQ);
    quant_x<<<M_TOK, 256, 0, stream>>>(x, xq, sx);
    pack_w<<<2048, 256, 0, stream>>>(wq, wq8, (long)N_OUT * K_DIM / 16);
    gemm_i8<<<dim3(NWG), dim3(512), 0, stream>>>(xq, wq8, sx, mx, bs, out);
  } else {
    dim3 grid(N_OUT / 128, M_TOK / 128);
    gemm_cvt<<<grid, 256, 0, stream>>>(x, wq, mx, bs, out);
  }
}